// Round 6
// baseline (406.585 us; speedup 1.0000x reference)
//
#include <hip/hip_runtime.h>
#include <math.h>

// PRNN J2 plane-strain elastoplasticity scan.
// B=16384, T=128, F=3, MATPTS=16 (P=262144), O=3.
// R6: R4 layout (2 packed points/thread, 8 lanes/batch, max wave count) but
// the cross-lane reduction is replaced by fire-and-forget LDS fp32 atomics
// into the consumed x-slots (zeroed one 4-step block at a time by a masked
// b128 write). No DPP, no selects, nothing on the critical path.
// BPB=16, block=128 -> 25 KB LDS, 1024 blocks, 2048 waves total.

#define BLOCK 128
#define BPB 16              // batch elements per block (8 lanes each)
#define TSTEPS 128
#define ROWF (TSTEPS * 3)   // 384 floats per batch row
#define ROWP 388            // padded stride: 16B-aligned; groups hit 8 distinct banks

typedef float v2 __attribute__((ext_vector_type(2)));

static __device__ __forceinline__ v2 vfma(v2 a, v2 b, v2 c) {
    return __builtin_elementwise_fma(a, b, c);
}
static __device__ __forceinline__ v2 vmax(v2 a, v2 b) {
    return __builtin_elementwise_max(a, b);
}
static __device__ __forceinline__ void lds_add(float* p, float v) {
    __hip_atomic_fetch_add(p, v, __ATOMIC_RELAXED, __HIP_MEMORY_SCOPE_WORKGROUP);
}

__global__ __launch_bounds__(BLOCK, 2)
void prnn_j2_kernel(const float* __restrict__ x,
                    const float* __restrict__ W1,
                    const float* __restrict__ W2,
                    float* __restrict__ out)
{
    constexpr float MU    = (float)(3130.0 / (2.0 * (1.0 + 0.37)));
    constexpr float LAM   = (float)(3130.0 * 0.37 / ((1.0 + 0.37) * (1.0 - 2.0 * 0.37)));
    constexpr float SIG_Y = 64.8f;
    constexpr float H_ISO = 300.0f;
    const float TWO_MU  = 2.0f * MU;
    const float INV_DEN = 1.0f / (3.0f * MU + H_ISO);
    const float K3P     = (3.0f * MU) * INV_DEN;   // k = K3P * f * rq
    const float HP      = H_ISO * INV_DEN;         // yld += HP * f
    const float KBULK   = LAM + TWO_MU * (1.0f / 3.0f);
    const float C_Q2    = 6.0f * MU * MU;

    // +12 floats: harmless one-block-over prefetch on the last iteration
    __shared__ float xs[BPB * ROWP + 12];

    const int tid = threadIdx.x;
    const int g   = tid >> 3;       // local batch 0..15
    const int l   = tid & 7;        // lane in 8-group; points (l, l+8)
    const int blockBase = blockIdx.x * (BPB * ROWF);

    // ---- stage x into LDS (coalesced float4 global reads) ----
    {
        const float4* xg = (const float4*)(x + blockBase);
        for (int i4 = tid; i4 < BPB * ROWF / 4; i4 += BLOCK) {
            int b  = i4 / (ROWF / 4);
            int r4 = i4 - b * (ROWF / 4);
            ((float4*)(xs + b * ROWP))[r4] = xg[i4];
        }
    }

    // ---- packed per-thread weights: .x = point l, .y = point l+8 ----
    const int pa = l, pb = l + 8;
    v2 w1p[3][3], w2p[3][3];
    #pragma unroll
    for (int c = 0; c < 3; ++c)
        #pragma unroll
        for (int f = 0; f < 3; ++f) {
            w1p[c][f].x = W1[(3 * pa + c) * 3 + f];
            w1p[c][f].y = W1[(3 * pb + c) * 3 + f];
        }
    #pragma unroll
    for (int o = 0; o < 3; ++o)
        #pragma unroll
        for (int c = 0; c < 3; ++c) {
            float wa = W2[o * 48 + 3 * pa + c];
            float wb = W2[o * 48 + 3 * pb + c];
            w2p[o][c].x = fmaxf(wa, 0.0f) + log1pf(expf(-fabsf(wa)));
            w2p[o][c].y = fmaxf(wb, 0.0f) + log1pf(expf(-fabsf(wb)));
        }

    __syncthreads();

    v2 p0 = {0.f,0.f}, p1 = {0.f,0.f}, p2 = {0.f,0.f}, p3 = {0.f,0.f};
    v2 yld = {SIG_Y, SIG_Y};
    float* xrow = &xs[g * ROWP];
    const float4* xv = (const float4*)xrow;   // g*1552 B, 16B aligned
    const bool zlane = (l < 3);
    float4* zp = (float4*)xrow + l;           // lane's zeroing slot within a block

#define J2_STEP(x0_, x1_, x2_, slot)                                         \
  {                                                                          \
    const float x0s = (x0_), x1s = (x1_), x2s = (x2_);                       \
    const v2 x0 = {x0s, x0s}, x1 = {x1s, x1s}, x2 = {x2s, x2s};              \
    const v2 e0 = vfma(w1p[0][0], x0, vfma(w1p[0][1], x1, w1p[0][2] * x2));  \
    const v2 e1 = vfma(w1p[1][0], x0, vfma(w1p[1][1], x1, w1p[1][2] * x2));  \
    const v2 e2 = vfma(w1p[2][0], x0, vfma(w1p[2][1], x1, w1p[2][2] * x2));  \
    const v2 ee_xx = e0 - p0;                                                \
    const v2 ee_yy = e1 - p1;                                                \
    const v2 ee_xy = 0.5f * e2 - p3;                                         \
    const v2 tr = (ee_xx + ee_yy) - p2;                                      \
    const v2 c3 = tr * (1.0f / 3.0f);                                        \
    const v2 exd = ee_xx - c3;                                               \
    const v2 eyd = ee_yy - c3;                                               \
    const v2 ezd = -p2 - c3;                                                 \
    v2 u = exd * exd;                                                        \
    u = vfma(eyd, eyd, u);                                                   \
    u = vfma(ezd, ezd, u);                                                   \
    u = vfma(ee_xy * ee_xy, (v2){2.0f, 2.0f}, u);                            \
    const v2 q2 = vmax(C_Q2 * u, (v2){1e-24f, 1e-24f});                      \
    v2 rq;                                                                   \
    rq.x = __builtin_amdgcn_rsqf(q2.x);                                      \
    rq.y = __builtin_amdgcn_rsqf(q2.y);                                      \
    const v2 q = q2 * rq;                                                    \
    const v2 f = vmax(q - yld, (v2){0.0f, 0.0f});                            \
    yld = vfma((v2){HP, HP}, f, yld);                                        \
    const v2 k   = (K3P * f) * rq;                                           \
    const v2 omk = 1.0f - k;                                                 \
    const v2 pm  = KBULK * tr;                                               \
    const v2 s0 = vfma(TWO_MU * exd, omk, pm);                               \
    const v2 s1 = vfma(TWO_MU * eyd, omk, pm);                               \
    const v2 s2 = (TWO_MU * ee_xy) * omk;                                    \
    p0 = vfma(k, exd, p0);                                                   \
    p1 = vfma(k, eyd, p1);                                                   \
    p2 = vfma(k, ezd, p2);                                                   \
    p3 = vfma(k, ee_xy, p3);                                                 \
    v2 r0 = vfma(w2p[0][0], s0, vfma(w2p[0][1], s1, w2p[0][2] * s2));        \
    v2 r1 = vfma(w2p[1][0], s0, vfma(w2p[1][1], s1, w2p[1][2] * s2));        \
    v2 r2 = vfma(w2p[2][0], s0, vfma(w2p[2][1], s1, w2p[2][2] * s2));        \
    lds_add(xrow + (slot) + 0, r0.x + r0.y);                                 \
    lds_add(xrow + (slot) + 1, r1.x + r1.y);                                 \
    lds_add(xrow + (slot) + 2, r2.x + r2.y);                                 \
  }

    float4 A0 = xv[0], A1 = xv[1], A2 = xv[2];
    for (int tb = 0; tb < TSTEPS / 4; ++tb) {
        // prefetch next 4-step block (last iter over-reads into pad)
        float4 An0 = xv[3 * tb + 3];
        float4 An1 = xv[3 * tb + 4];
        float4 An2 = xv[3 * tb + 5];

        // zero this block's 12 output slots (consumed into regs last iter);
        // same-wave LDS program order puts this before the atomics below.
        if (zlane) zp[3 * tb] = (float4){0.f, 0.f, 0.f, 0.f};

        const int wo = 12 * tb;
        J2_STEP(A0.x, A0.y, A0.z, wo + 0);
        J2_STEP(A0.w, A1.x, A1.y, wo + 3);
        J2_STEP(A1.z, A1.w, A2.x, wo + 6);
        J2_STEP(A2.y, A2.z, A2.w, wo + 9);

        A0 = An0; A1 = An1; A2 = An2;
    }
#undef J2_STEP

    __syncthreads();

    // ---- coalesced float4 flush LDS -> out ----
    {
        float4* og = (float4*)(out + blockBase);
        for (int i4 = tid; i4 < BPB * ROWF / 4; i4 += BLOCK) {
            int b  = i4 / (ROWF / 4);
            int r4 = i4 - b * (ROWF / 4);
            og[i4] = ((const float4*)(xs + b * ROWP))[r4];
        }
    }
}

extern "C" void kernel_launch(void* const* d_in, const int* in_sizes, int n_in,
                              void* d_out, int out_size, void* d_ws, size_t ws_size,
                              hipStream_t stream) {
    const float* x  = (const float*)d_in[0];
    const float* W1 = (const float*)d_in[1];
    const float* W2 = (const float*)d_in[2];
    float* out = (float*)d_out;

    const int B = 16384;
    dim3 grid(B / BPB);   // 1024 blocks
    dim3 block(BLOCK);
    prnn_j2_kernel<<<grid, block, 0, stream>>>(x, W1, W2, out);
}

// Round 7
// 120.541 us; speedup vs baseline: 3.3730x; 3.3730x over previous
//
#include <hip/hip_runtime.h>
#include <math.h>

// PRNN J2 plane-strain elastoplasticity scan.
// B=16384, T=128, F=3, MATPTS=16 (P=262144), O=3.
// R7: R4 layout (2 packed points/thread, 8 lanes/batch, 32 batches/block,
// 2 waves/SIMD) with the cross-lane reduction BATCHED: physics for 4 steps
// runs back-to-back, then ONE 12-register DPP butterfly block (12-way
// interleave -> no internal stalls, one scheduling barrier per 4 steps).

#define BLOCK 256
#define BPB 32              // batch elements per block (8 lanes each)
#define TSTEPS 128
#define ROWF (TSTEPS * 3)   // 384 floats per batch row
#define ROWP 388            // padded stride: 16B-aligned

typedef float v2 __attribute__((ext_vector_type(2)));

static __device__ __forceinline__ v2 vfma(v2 a, v2 b, v2 c) {
    return __builtin_elementwise_fma(a, b, c);
}
static __device__ __forceinline__ v2 vmax(v2 a, v2 b) {
    return __builtin_elementwise_max(a, b);
}

// 8-lane butterfly sum of TWELVE scalars via fused DPP adds.
// Stages: quad_perm xor1, quad_perm xor2 (intra-quad), row_half_mirror
// (cross-quad). 12-way interleave => 11 instructions between a register's
// consecutive stages (hazard needs 2; ~4-8 cyc DPP latency fully hidden).
#define DPP_ST(r, ctrl) "v_add_f32_dpp %" #r ", %" #r ", %" #r " " ctrl \
                        " row_mask:0xf bank_mask:0xf\n\t"
#define DPP_STAGE(ctrl) \
    DPP_ST(0, ctrl) DPP_ST(1, ctrl) DPP_ST(2, ctrl)  DPP_ST(3, ctrl) \
    DPP_ST(4, ctrl) DPP_ST(5, ctrl) DPP_ST(6, ctrl)  DPP_ST(7, ctrl) \
    DPP_ST(8, ctrl) DPP_ST(9, ctrl) DPP_ST(10, ctrl) DPP_ST(11, ctrl)
#define DPP_BFLY12(a0,a1,a2,a3,a4,a5,a6,a7,a8,a9,a10,a11)                    \
  asm volatile(                                                              \
    "s_nop 1\n\t"                                                            \
    DPP_STAGE("quad_perm:[1,0,3,2]")                                         \
    DPP_STAGE("quad_perm:[2,3,0,1]")                                         \
    DPP_STAGE("row_half_mirror")                                             \
    : "+v"(a0), "+v"(a1), "+v"(a2), "+v"(a3), "+v"(a4), "+v"(a5),            \
      "+v"(a6), "+v"(a7), "+v"(a8), "+v"(a9), "+v"(a10), "+v"(a11))

__global__ __launch_bounds__(BLOCK, 2)
void prnn_j2_kernel(const float* __restrict__ x,
                    const float* __restrict__ W1,
                    const float* __restrict__ W2,
                    float* __restrict__ out)
{
    constexpr float MU    = (float)(3130.0 / (2.0 * (1.0 + 0.37)));
    constexpr float LAM   = (float)(3130.0 * 0.37 / ((1.0 + 0.37) * (1.0 - 2.0 * 0.37)));
    constexpr float SIG_Y = 64.8f;
    constexpr float H_ISO = 300.0f;
    const float TWO_MU  = 2.0f * MU;
    const float INV_DEN = 1.0f / (3.0f * MU + H_ISO);
    const float K3P     = (3.0f * MU) * INV_DEN;   // k = K3P * f * rq
    const float HP      = H_ISO * INV_DEN;         // yld += HP * f
    const float KBULK   = LAM + TWO_MU * (1.0f / 3.0f);
    const float C_Q2    = 6.0f * MU * MU;

    // +12 floats: harmless one-block-over prefetch on the last iteration
    __shared__ float xs[BPB * ROWP + 12];

    const int tid = threadIdx.x;
    const int g   = tid >> 3;       // local batch 0..31
    const int l   = tid & 7;        // lane in 8-group; points (l, l+8)
    const int blockBase = blockIdx.x * (BPB * ROWF);

    // ---- stage x into LDS (coalesced float4 global reads) ----
    {
        const float4* xg = (const float4*)(x + blockBase);
        for (int i4 = tid; i4 < BPB * ROWF / 4; i4 += BLOCK) {
            int b  = i4 / (ROWF / 4);
            int r4 = i4 - b * (ROWF / 4);
            ((float4*)(xs + b * ROWP))[r4] = xg[i4];
        }
    }

    // ---- packed per-thread weights: .x = point l, .y = point l+8 ----
    const int pa = l, pb = l + 8;
    v2 w1p[3][3], w2p[3][3];
    #pragma unroll
    for (int c = 0; c < 3; ++c)
        #pragma unroll
        for (int f = 0; f < 3; ++f) {
            w1p[c][f].x = W1[(3 * pa + c) * 3 + f];
            w1p[c][f].y = W1[(3 * pb + c) * 3 + f];
        }
    #pragma unroll
    for (int o = 0; o < 3; ++o)
        #pragma unroll
        for (int c = 0; c < 3; ++c) {
            float wa = W2[o * 48 + 3 * pa + c];
            float wb = W2[o * 48 + 3 * pb + c];
            w2p[o][c].x = fmaxf(wa, 0.0f) + log1pf(expf(-fabsf(wa)));
            w2p[o][c].y = fmaxf(wb, 0.0f) + log1pf(expf(-fabsf(wb)));
        }

    __syncthreads();

    v2 p0 = {0.f,0.f}, p1 = {0.f,0.f}, p2 = {0.f,0.f}, p3 = {0.f,0.f};
    v2 yld = {SIG_Y, SIG_Y};
    float* xrow = &xs[g * ROWP];
    const float4* xv = (const float4*)xrow;   // g*1552 B, 16B aligned
    const bool wact = (l < 3);

    // physics for one step: consumes (x0,x1,x2), updates state, emits folded
    // per-thread partial outputs o0,o1,o2
#define J2_PHYS(x0_, x1_, x2_, o0_, o1_, o2_)                                \
  {                                                                          \
    const float x0s = (x0_), x1s = (x1_), x2s = (x2_);                       \
    const v2 x0 = {x0s, x0s}, x1 = {x1s, x1s}, x2 = {x2s, x2s};              \
    const v2 e0 = vfma(w1p[0][0], x0, vfma(w1p[0][1], x1, w1p[0][2] * x2));  \
    const v2 e1 = vfma(w1p[1][0], x0, vfma(w1p[1][1], x1, w1p[1][2] * x2));  \
    const v2 e2 = vfma(w1p[2][0], x0, vfma(w1p[2][1], x1, w1p[2][2] * x2));  \
    const v2 ee_xx = e0 - p0;                                                \
    const v2 ee_yy = e1 - p1;                                                \
    const v2 ee_xy = 0.5f * e2 - p3;                                         \
    const v2 tr = (ee_xx + ee_yy) - p2;                                      \
    const v2 c3 = tr * (1.0f / 3.0f);                                        \
    const v2 exd = ee_xx - c3;                                               \
    const v2 eyd = ee_yy - c3;                                               \
    const v2 ezd = -p2 - c3;                                                 \
    v2 u = exd * exd;                                                        \
    u = vfma(eyd, eyd, u);                                                   \
    u = vfma(ezd, ezd, u);                                                   \
    u = vfma(ee_xy * ee_xy, (v2){2.0f, 2.0f}, u);                            \
    const v2 q2 = vmax(C_Q2 * u, (v2){1e-24f, 1e-24f});                      \
    v2 rq;                                                                   \
    rq.x = __builtin_amdgcn_rsqf(q2.x);                                      \
    rq.y = __builtin_amdgcn_rsqf(q2.y);                                      \
    const v2 q = q2 * rq;                                                    \
    const v2 f = vmax(q - yld, (v2){0.0f, 0.0f});                            \
    yld = vfma((v2){HP, HP}, f, yld);                                        \
    const v2 k   = (K3P * f) * rq;                                           \
    const v2 omk = 1.0f - k;                                                 \
    const v2 pm  = KBULK * tr;                                               \
    const v2 s0 = vfma(TWO_MU * exd, omk, pm);                               \
    const v2 s1 = vfma(TWO_MU * eyd, omk, pm);                               \
    const v2 s2 = (TWO_MU * ee_xy) * omk;                                    \
    p0 = vfma(k, exd, p0);                                                   \
    p1 = vfma(k, eyd, p1);                                                   \
    p2 = vfma(k, ezd, p2);                                                   \
    p3 = vfma(k, ee_xy, p3);                                                 \
    v2 r0 = vfma(w2p[0][0], s0, vfma(w2p[0][1], s1, w2p[0][2] * s2));        \
    v2 r1 = vfma(w2p[1][0], s0, vfma(w2p[1][1], s1, w2p[1][2] * s2));        \
    v2 r2 = vfma(w2p[2][0], s0, vfma(w2p[2][1], s1, w2p[2][2] * s2));        \
    o0_ = r0.x + r0.y;                                                       \
    o1_ = r1.x + r1.y;                                                       \
    o2_ = r2.x + r2.y;                                                       \
  }

    float4 A0 = xv[0], A1 = xv[1], A2 = xv[2];
    for (int tb = 0; tb < TSTEPS / 4; ++tb) {
        // prefetch next 4-step block (last iter over-reads into pad)
        float4 An0 = xv[3 * tb + 3];
        float4 An1 = xv[3 * tb + 4];
        float4 An2 = xv[3 * tb + 5];

        float o00, o01, o02, o10, o11, o12, o20, o21, o22, o30, o31, o32;
        J2_PHYS(A0.x, A0.y, A0.z, o00, o01, o02);
        J2_PHYS(A0.w, A1.x, A1.y, o10, o11, o12);
        J2_PHYS(A1.z, A1.w, A2.x, o20, o21, o22);
        J2_PHYS(A2.y, A2.z, A2.w, o30, o31, o32);

        // one fused-DPP reduction for all 12 outputs; all lanes end with sums
        DPP_BFLY12(o00, o01, o02, o10, o11, o12,
                   o20, o21, o22, o30, o31, o32);

        // lanes 0..2 write component l for each of the 4 steps
        if (wact) {
            float* wp = xrow + 12 * tb + l;
            float v0 = (l == 1) ? o01 : o00;  v0 = (l == 2) ? o02 : v0;
            float v1 = (l == 1) ? o11 : o10;  v1 = (l == 2) ? o12 : v1;
            float v2s = (l == 1) ? o21 : o20; v2s = (l == 2) ? o22 : v2s;
            float v3 = (l == 1) ? o31 : o30;  v3 = (l == 2) ? o32 : v3;
            wp[0] = v0;  wp[3] = v1;  wp[6] = v2s;  wp[9] = v3;
        }

        A0 = An0; A1 = An1; A2 = An2;
    }
#undef J2_PHYS

    __syncthreads();

    // ---- coalesced float4 flush LDS -> out ----
    {
        float4* og = (float4*)(out + blockBase);
        for (int i4 = tid; i4 < BPB * ROWF / 4; i4 += BLOCK) {
            int b  = i4 / (ROWF / 4);
            int r4 = i4 - b * (ROWF / 4);
            og[i4] = ((const float4*)(xs + b * ROWP))[r4];
        }
    }
}

extern "C" void kernel_launch(void* const* d_in, const int* in_sizes, int n_in,
                              void* d_out, int out_size, void* d_ws, size_t ws_size,
                              hipStream_t stream) {
    const float* x  = (const float*)d_in[0];
    const float* W1 = (const float*)d_in[1];
    const float* W2 = (const float*)d_in[2];
    float* out = (float*)d_out;

    const int B = 16384;
    dim3 grid(B / BPB);   // 512 blocks
    dim3 block(BLOCK);
    prnn_j2_kernel<<<grid, block, 0, stream>>>(x, W1, W2, out);
}